// Round 3
// baseline (86.860 us; speedup 1.0000x reference)
//
#include <hip/hip_runtime.h>
#include <hip/hip_bf16.h>

// Problem constants (JointAnfisNet)
#define BATCH      16384
#define N_IN       6
#define N_MF       5
#define N_FUZZ     30      // N_IN * N_MF
#define N_RULES    2048

#define ROWS_PER_BLOCK 64
#define BLOCK_THREADS  1024
#define WAVES          (BLOCK_THREADS / 64)          // 16
#define RULES_PER_WAVE (N_RULES / WAVES)             // 128

// ---------------------------------------------------------------------------
// Single fused kernel. Handles BOTH possible harness dtypes (bf16 / float32)
// via a deterministic runtime probe, and uses NO global workspace (d_ws was a
// suspect for the R2 NaN: 24 KB of writes into a buffer of unknown size).
//
// Block = 64 rows x all 2048 rules.
//   lane (0..63) = row, wave (0..15) = chunk of 128 rules (wave-uniform rule
//   loop -> packed/ow LDS reads are broadcast, conflict-free).
// fuzz LDS [30][64]: gather addr = uniform*256B + lane*4B -> bank = lane%32,
// exactly 2 lanes/bank => free 2-way access (m136).
// ---------------------------------------------------------------------------
__global__ __launch_bounds__(BLOCK_THREADS, 1)
void anfis_kernel(const void* __restrict__ x_,            // [BATCH][N_IN]  bf16 or f32
                  const void* __restrict__ mfc_,          // [30]           bf16 or f32
                  const void* __restrict__ mfs_,          // [30]           bf16 or f32
                  const void* __restrict__ oc_,           // [12]           bf16 or f32
                  const int*  __restrict__ input_rules,   // [N_RULES][6]   int32
                  const int*  __restrict__ output_rules,  // [N_RULES][2]   int32
                  void* __restrict__ out_) {              // [BATCH][2]     bf16 or f32
    __shared__ float        fuzz[N_FUZZ][ROWS_PER_BLOCK];   // 7.5 KB
    __shared__ float        p_l1[WAVES][ROWS_PER_BLOCK];    // 4 KB
    __shared__ float        p_d0[WAVES][ROWS_PER_BLOCK];    // 4 KB
    __shared__ float        p_d1[WAVES][ROWS_PER_BLOCK];    // 4 KB
    __shared__ unsigned int packed_lds[N_RULES];            // 8 KB
    __shared__ float2       ow_lds[N_RULES];                // 16 KB
    __shared__ int          dtype_flag;                     // 1 = bf16, 0 = f32

    const int t    = threadIdx.x;
    const int row0 = blockIdx.x * ROWS_PER_BLOCK;

    // ---- Stage A: dtype probe. mf_scales is genuinely in [0.5, 1.5].
    // Read its first 60 bytes (valid under both dtypes) as 30 bf16 halves:
    // genuine bf16 -> all in [0.4,1.6]; genuine f32 -> low-mantissa halves
    // are random bf16 patterns, all-in-range has P ~ 1e-32.
    if (t == 0) {
        const unsigned int* w = (const unsigned int*)mfs_;
        int ok = 1;
        for (int k = 0; k < 15; ++k) {
            const unsigned int v = w[k];
            const float lo = __uint_as_float(v << 16);
            const float hi = __uint_as_float(v & 0xffff0000u);
            if (!(lo >= 0.4f && lo <= 1.6f && hi >= 0.4f && hi <= 1.6f)) { ok = 0; break; }
        }
        dtype_flag = ok;
    }
    __syncthreads();
    const bool is_bf16 = (dtype_flag != 0);

    // ---- Stage B1: rule prep into LDS (2 rules/thread). Rules are shared by
    // all rows; arrays are tiny -> L2-resident across the 256 blocks.
    for (int r = t; r < N_RULES; r += BLOCK_THREADS) {
        const int* rp = input_rules + r * N_IN;
        unsigned int p = 0;
#pragma unroll
        for (int i = 0; i < N_IN; ++i) {
            p |= ((unsigned int)rp[i] & 31u) << (5 * i);
        }
        packed_lds[r] = p;
        const int o0i = output_rules[2 * r + 0];
        const int o1i = output_rules[2 * r + 1];
        float o0, o1;
        if (is_bf16) {
            const unsigned short* oc = (const unsigned short*)oc_;
            o0 = __uint_as_float((unsigned int)oc[o0i] << 16);
            o1 = __uint_as_float((unsigned int)oc[o1i] << 16);
        } else {
            const float* oc = (const float*)oc_;
            o0 = oc[o0i];
            o1 = oc[o1i];
        }
        ow_lds[r] = make_float2(o0, o1);
    }

    // ---- Stage B2: fuzzification. 1920 (v,row) pairs, 1024 threads -> 2 iters.
    for (int idx = t; idx < N_FUZZ * ROWS_PER_BLOCK; idx += BLOCK_THREADS) {
        const int v   = idx >> 6;     // 0..29 : flattened (input, mf) index
        const int row = idx & 63;
        const int i   = v / N_MF;     // input index
        float xv, c, s;
        if (is_bf16) {
            const unsigned short* xp = (const unsigned short*)x_;
            const unsigned short* cp = (const unsigned short*)mfc_;
            const unsigned short* sp = (const unsigned short*)mfs_;
            xv = __uint_as_float((unsigned int)xp[(row0 + row) * N_IN + i] << 16);
            c  = __uint_as_float((unsigned int)cp[v] << 16);
            s  = __uint_as_float((unsigned int)sp[v] << 16);
        } else {
            xv = ((const float*)x_)[(row0 + row) * N_IN + i];
            c  = ((const float*)mfc_)[v];
            s  = ((const float*)mfs_)[v];
        }
        const float z = (xv - c) / s;
        fuzz[v][row] = __expf(-z * z);
    }
    __syncthreads();

    // ---- Stage C: rule evaluation. wave-uniform rule loop. ----
    const int lane = t & 63;
    const int wave = __builtin_amdgcn_readfirstlane(t >> 6);

    float acc_l1 = 0.0f, acc_d0 = 0.0f, acc_d1 = 0.0f;
    const int rbase = wave * RULES_PER_WAVE;
#pragma unroll 4
    for (int j = 0; j < RULES_PER_WAVE; ++j) {
        const int r = rbase + j;
        const unsigned int p = packed_lds[r];   // broadcast LDS read (uniform)
        const float2 o = ow_lds[r];             // broadcast LDS read (uniform)
        float w = fuzz[p & 31u][lane];
        w = fminf(w, fuzz[(p >> 5)  & 31u][lane]);
        w = fminf(w, fuzz[(p >> 10) & 31u][lane]);
        w = fminf(w, fuzz[(p >> 15) & 31u][lane]);
        w = fminf(w, fuzz[(p >> 20) & 31u][lane]);
        w = fminf(w, fuzz[(p >> 25) & 31u][lane]);
        acc_l1 += w;            // w >= 0 so |w| == w
        acc_d0 += w * o.x;
        acc_d1 += w * o.y;
    }
    p_l1[wave][lane] = acc_l1;
    p_d0[wave][lane] = acc_d0;
    p_d1[wave][lane] = acc_d1;
    __syncthreads();

    // ---- Stage D: reduce 16 wave-partials per row, finalize, store ----
    if (t < ROWS_PER_BLOCK) {
        float l1 = 0.0f, d0 = 0.0f, d1 = 0.0f;
#pragma unroll
        for (int wv = 0; wv < WAVES; ++wv) {
            l1 += p_l1[wv][t];
            d0 += p_d0[wv][t];
            d1 += p_d1[wv][t];
        }
        const float inv = 1.0f / fmaxf(l1, 1e-12f);
        const float y0 = tanhf(d0 * inv) * 4.00f + 0.00f;
        const float y1 = tanhf(d1 * inv) * 0.75f + 0.75f;
        if (is_bf16) {
            __hip_bfloat162 o;
            o.x = __float2bfloat16(y0);
            o.y = __float2bfloat16(y1);
            ((__hip_bfloat162*)out_)[row0 + t] = o;
        } else {
            ((float2*)out_)[row0 + t] = make_float2(y0, y1);
        }
    }
}

extern "C" void kernel_launch(void* const* d_in, const int* in_sizes, int n_in,
                              void* d_out, int out_size, void* d_ws, size_t ws_size,
                              hipStream_t stream) {
    (void)d_ws; (void)ws_size; (void)in_sizes; (void)n_in; (void)out_size;
    anfis_kernel<<<BATCH / ROWS_PER_BLOCK, BLOCK_THREADS, 0, stream>>>(
        d_in[0], d_in[1], d_in[2], d_in[3],
        (const int*)d_in[4], (const int*)d_in[5],
        d_out);
}

// Round 5
// 80.956 us; speedup vs baseline: 1.0729x; 1.0729x over previous
//
#include <hip/hip_runtime.h>
#include <hip/hip_bf16.h>

// Problem constants (JointAnfisNet)
#define BATCH      16384
#define N_IN       6
#define N_MF       5
#define N_FUZZ     30      // N_IN * N_MF
#define N_RULES    2048
#define N_OUT_MEM  12

// Main-kernel decomposition:
//   256 rows/block, 4 rows per lane packed as f16x4 (uint2) -> one ds_read_b64
//   serves 4 rows. Rules split 4 ways across blocks so grid stays 256 = 64 row
//   groups x 4 rule splits (fills all 256 CUs). Partials combined by finalize.
#define ROWS_PB    256
#define SPLITS     4
#define RULES_PB   (N_RULES / SPLITS)     // 512
#define THREADS    1024
#define WAVES      16
#define RULES_PW   (RULES_PB / WAVES)     // 32
#define ROWGROUPS  (BATCH / ROWS_PB)      // 64

// d_ws layout (ws_size ~256 MB per R3 WRITE_SIZE evidence; we use <1 MB)
#define WS_PACKED_OFF  0                       // u32[2048]    = 8 KB
#define WS_OW_OFF      8192                    // float2[2048] = 16 KB
#define WS_PART_OFF    24576                   // f32[SPLITS*3*BATCH] = 768 KB

// Packed f16 pair, header-independent. __builtin_elementwise_min lowers to
// v_pk_min_f16 on gfx950 (R4 failed because amd_hip_fp16.h has no __hmin2).
typedef _Float16 f16x2 __attribute__((ext_vector_type(2)));

// ---------------------------------------------------------------------------
// Deterministic dtype probe: mf_scales is genuinely in [0.5, 1.5]. Interpret
// its first 60 bytes as 30 bf16 halves; all-in-[0.4,1.6] => bf16 data
// (P(false positive for f32 data) ~ 1e-32). R3 passed with this probe
// (probe reported f32: absmax 4.9e-4 is f32-compute scale).
// ---------------------------------------------------------------------------
__device__ inline int probe_is_bf16(const void* mfs) {
    const unsigned int* w = (const unsigned int*)mfs;
    int ok = 1;
    for (int k = 0; k < 15; ++k) {
        const unsigned int v = w[k];
        const float lo = __uint_as_float(v << 16);
        const float hi = __uint_as_float(v & 0xffff0000u);
        if (!(lo >= 0.4f && lo <= 1.6f && hi >= 0.4f && hi <= 1.6f)) { ok = 0; break; }
    }
    return ok;
}

// ---------------------------------------------------------------------------
// Prep: pack each rule's 6 MF indices (5 bits each) into u32, pre-gather
// out_centers[output_rules] -> float2. Written to d_ws so the main kernel's
// wave-uniform rule loop reads them via the SCALAR pipe (s_load), not LDS.
// ---------------------------------------------------------------------------
__global__ void anfis_prep(const int* __restrict__ input_rules,
                           const int* __restrict__ output_rules,
                           const void* __restrict__ oc_,
                           const void* __restrict__ mfs_,
                           unsigned int* __restrict__ packed,
                           float2* __restrict__ ow) {
    __shared__ int flag;
    if (threadIdx.x == 0) flag = probe_is_bf16(mfs_);
    __syncthreads();
    const bool is_bf16 = (flag != 0);

    const int r = blockIdx.x * blockDim.x + threadIdx.x;
    if (r >= N_RULES) return;
    const int* rp = input_rules + r * N_IN;
    unsigned int p = 0;
#pragma unroll
    for (int i = 0; i < N_IN; ++i) p |= ((unsigned int)rp[i] & 31u) << (5 * i);
    packed[r] = p;

    const int o0i = output_rules[2 * r + 0];
    const int o1i = output_rules[2 * r + 1];
    float o0, o1;
    if (is_bf16) {
        const unsigned short* oc = (const unsigned short*)oc_;
        o0 = __uint_as_float((unsigned int)oc[o0i] << 16);
        o1 = __uint_as_float((unsigned int)oc[o1i] << 16);
    } else {
        const float* oc = (const float*)oc_;
        o0 = oc[o0i]; o1 = oc[o1i];
    }
    ow[r] = make_float2(o0, o1);
}

// ---------------------------------------------------------------------------
// Main: block = (row group g: 256 rows) x (rule split s: 512 rules).
//   lane (0..63) covers rows {l, l+64, l+128, l+192} packed as f16x4 in uint2.
//   wave (0..15) handles 32 rules; rule index wave-uniform -> packed/ow come
//   in via the scalar pipe; the 6 fuzz gathers are ds_read_b64, conflict-free
//   (64 lanes x 8 B sweep all 32 banks in two clean passes).
// ---------------------------------------------------------------------------
__global__ __launch_bounds__(THREADS, 4)
void anfis_main(const void* __restrict__ x_,
                const void* __restrict__ mfc_,
                const void* __restrict__ mfs_,
                const unsigned int* __restrict__ packed,
                const float2* __restrict__ ow,
                float* __restrict__ partials) {
    __shared__ float xs[ROWS_PB * N_IN];       // 6 KB staged x
    __shared__ float2 cinv[N_FUZZ];            // (center, 1/scale)
    __shared__ uint2 fuzz4[N_FUZZ][64];        // 15 KB, 4 rows/lane as f16x4
    __shared__ float pl1[WAVES][ROWS_PB];      // 16 KB
    __shared__ float pd0[WAVES][ROWS_PB];      // 16 KB
    __shared__ float pd1[WAVES][ROWS_PB];      // 16 KB
    __shared__ int flag;

    const int t     = threadIdx.x;
    const int g     = blockIdx.x >> 2;         // row group 0..63
    const int split = blockIdx.x & 3;          // rule split 0..3
    const int row0  = g * ROWS_PB;

    if (t == 0) flag = probe_is_bf16(mfs_);
    __syncthreads();
    const bool is_bf16 = (flag != 0);

    // ---- stage x rows + MF params into LDS ----
    if (is_bf16) {
        const unsigned short* xp = (const unsigned short*)x_ + row0 * N_IN;
        for (int i = t; i < ROWS_PB * N_IN; i += THREADS)
            xs[i] = __uint_as_float((unsigned int)xp[i] << 16);
    } else {
        const float* xp = (const float*)x_ + row0 * N_IN;
        for (int i = t; i < ROWS_PB * N_IN; i += THREADS) xs[i] = xp[i];
    }
    if (t < N_FUZZ) {
        float c, s;
        if (is_bf16) {
            c = __uint_as_float((unsigned int)((const unsigned short*)mfc_)[t] << 16);
            s = __uint_as_float((unsigned int)((const unsigned short*)mfs_)[t] << 16);
        } else {
            c = ((const float*)mfc_)[t];
            s = ((const float*)mfs_)[t];
        }
        cinv[t] = make_float2(c, 1.0f / s);
    }
    __syncthreads();

    // ---- fuzzify: 30 x 64 uint2 entries, each = 4 rows' exp(-z^2) as f16 ----
    for (int e = t; e < N_FUZZ * 64; e += THREADS) {
        const int v    = e >> 6;    // MF value index 0..29
        const int lane = e & 63;
        const int i    = v / N_MF;  // input index
        const float2 ci = cinv[v];
        float f[4];
#pragma unroll
        for (int k = 0; k < 4; ++k) {
            const float z = (xs[(lane + 64 * k) * N_IN + i] - ci.x) * ci.y;
            f[k] = __expf(-z * z);
        }
        f16x2 a = { (_Float16)f[0], (_Float16)f[1] };   // rows lane, lane+64
        f16x2 b = { (_Float16)f[2], (_Float16)f[3] };   // rows lane+128, +192
        uint2 u;
        u.x = __builtin_bit_cast(unsigned int, a);
        u.y = __builtin_bit_cast(unsigned int, b);
        fuzz4[v][lane] = u;
    }
    __syncthreads();

    // ---- rule loop: wave-uniform r -> scalar packed/ow, 6 b64 gathers ----
    const int lane = t & 63;
    const int wave = __builtin_amdgcn_readfirstlane(t >> 6);
    const uint2* fz = &fuzz4[0][0];

    float l1[4] = {0.f, 0.f, 0.f, 0.f};
    float d0[4] = {0.f, 0.f, 0.f, 0.f};
    float d1[4] = {0.f, 0.f, 0.f, 0.f};

    const int rbase = split * RULES_PB + wave * RULES_PW;
#pragma unroll 4
    for (int j = 0; j < RULES_PW; ++j) {
        const int r = rbase + j;
        const unsigned int p = packed[r];   // uniform -> scalar load
        const float2 o = ow[r];             // uniform -> scalar load
        const uint2 g0 = fz[((p      ) & 31u) * 64 + lane];
        const uint2 g1 = fz[((p >> 5 ) & 31u) * 64 + lane];
        const uint2 g2 = fz[((p >> 10) & 31u) * 64 + lane];
        const uint2 g3 = fz[((p >> 15) & 31u) * 64 + lane];
        const uint2 g4 = fz[((p >> 20) & 31u) * 64 + lane];
        const uint2 g5 = fz[((p >> 25) & 31u) * 64 + lane];
        f16x2 wa = __builtin_elementwise_min(__builtin_bit_cast(f16x2, g0.x),
                                             __builtin_bit_cast(f16x2, g1.x));
        wa = __builtin_elementwise_min(wa, __builtin_bit_cast(f16x2, g2.x));
        wa = __builtin_elementwise_min(wa, __builtin_bit_cast(f16x2, g3.x));
        wa = __builtin_elementwise_min(wa, __builtin_bit_cast(f16x2, g4.x));
        wa = __builtin_elementwise_min(wa, __builtin_bit_cast(f16x2, g5.x));
        f16x2 wb = __builtin_elementwise_min(__builtin_bit_cast(f16x2, g0.y),
                                             __builtin_bit_cast(f16x2, g1.y));
        wb = __builtin_elementwise_min(wb, __builtin_bit_cast(f16x2, g2.y));
        wb = __builtin_elementwise_min(wb, __builtin_bit_cast(f16x2, g3.y));
        wb = __builtin_elementwise_min(wb, __builtin_bit_cast(f16x2, g4.y));
        wb = __builtin_elementwise_min(wb, __builtin_bit_cast(f16x2, g5.y));
        const float w0 = (float)wa.x, w1 = (float)wa.y;
        const float w2 = (float)wb.x, w3 = (float)wb.y;
        l1[0] += w0; d0[0] += w0 * o.x; d1[0] += w0 * o.y;
        l1[1] += w1; d0[1] += w1 * o.x; d1[1] += w1 * o.y;
        l1[2] += w2; d0[2] += w2 * o.x; d1[2] += w2 * o.y;
        l1[3] += w3; d0[3] += w3 * o.x; d1[3] += w3 * o.y;
    }
#pragma unroll
    for (int k = 0; k < 4; ++k) {
        pl1[wave][lane + 64 * k] = l1[k];
        pd0[wave][lane + 64 * k] = d0[k];
        pd1[wave][lane + 64 * k] = d1[k];
    }
    __syncthreads();

    // ---- block reduction over 16 waves; write split partials ----
    if (t < ROWS_PB) {
        float a = 0.f, b = 0.f, c = 0.f;
#pragma unroll
        for (int wv = 0; wv < WAVES; ++wv) {
            a += pl1[wv][t];
            b += pd0[wv][t];
            c += pd1[wv][t];
        }
        const int row = row0 + t;
        partials[(split * 3 + 0) * BATCH + row] = a;
        partials[(split * 3 + 1) * BATCH + row] = b;
        partials[(split * 3 + 2) * BATCH + row] = c;
    }
}

// ---------------------------------------------------------------------------
// Finalize: sum the 4 rule-split partials per row, normalize, tanh, store.
// ---------------------------------------------------------------------------
__global__ void anfis_finalize(const float* __restrict__ partials,
                               const void* __restrict__ mfs_,
                               void* __restrict__ out_) {
    __shared__ int flag;
    if (threadIdx.x == 0) flag = probe_is_bf16(mfs_);
    __syncthreads();
    const int row = blockIdx.x * blockDim.x + threadIdx.x;
    if (row >= BATCH) return;
    float l1 = 0.f, d0 = 0.f, d1 = 0.f;
#pragma unroll
    for (int s = 0; s < SPLITS; ++s) {
        l1 += partials[(s * 3 + 0) * BATCH + row];
        d0 += partials[(s * 3 + 1) * BATCH + row];
        d1 += partials[(s * 3 + 2) * BATCH + row];
    }
    const float inv = 1.0f / fmaxf(l1, 1e-12f);
    const float y0 = tanhf(d0 * inv) * 4.00f + 0.00f;
    const float y1 = tanhf(d1 * inv) * 0.75f + 0.75f;
    if (flag) {
        __hip_bfloat162 o;
        o.x = __float2bfloat16(y0);
        o.y = __float2bfloat16(y1);
        ((__hip_bfloat162*)out_)[row] = o;
    } else {
        ((float2*)out_)[row] = make_float2(y0, y1);
    }
}

extern "C" void kernel_launch(void* const* d_in, const int* in_sizes, int n_in,
                              void* d_out, int out_size, void* d_ws, size_t ws_size,
                              hipStream_t stream) {
    (void)in_sizes; (void)n_in; (void)out_size; (void)ws_size;
    const void* x_   = d_in[0];
    const void* mfc_ = d_in[1];
    const void* mfs_ = d_in[2];
    const void* oc_  = d_in[3];
    const int* input_rules  = (const int*)d_in[4];
    const int* output_rules = (const int*)d_in[5];

    unsigned int* packed = (unsigned int*)((char*)d_ws + WS_PACKED_OFF);
    float2*       ow     = (float2*)((char*)d_ws + WS_OW_OFF);
    float*        parts  = (float*)((char*)d_ws + WS_PART_OFF);

    anfis_prep<<<(N_RULES + 255) / 256, 256, 0, stream>>>(
        input_rules, output_rules, oc_, mfs_, packed, ow);

    anfis_main<<<ROWGROUPS * SPLITS, THREADS, 0, stream>>>(
        x_, mfc_, mfs_, packed, ow, parts);

    anfis_finalize<<<BATCH / 256, 256, 0, stream>>>(parts, mfs_, d_out);
}